// Round 6
// baseline (365.536 us; speedup 1.0000x reference)
//
#include <hip/hip_runtime.h>

#define NT    8192   // tokens
#define CIN   4096   // in_channel
#define COUT  4096   // out_channel
#define RK    16     // rank
#define ROWS  8      // tokens per block -> grid 1024 = 4 blocks/CU
#define CHUNK 256    // k per chunk (lane l owns k = c*256 + l*4 .. +3)
#define NCHUNK (CIN / CHUNK)   // 16
#define RST   36     // red row stride (floats): bank = 4*l -> 2-way = free

// ---------------------------------------------------------------------------
// Fused out = (x @ right^T) @ left^T + bias. One kernel, no workspace.
// grid = 1024 (8-token groups), 256 threads (4 waves).
//
// Phase 1 — BARRIER-FREE streaming: no LDS, no double-buffer, no gload_lds.
//   rgt is 256 KB (L1/L2-resident: all 4 waves of a block re-read the same
//   16 KB chunk; all in-flight blocks read the same 256 KB). Per chunk:
//   2 coalesced x float4 (HBM stream) + 16 coalesced rgt float4 (cache hits)
//   + 128 fmac into acc[2][16]. Waves slip freely -> latency hidden by TLP,
//   not by a register-hungry software pipeline.
//   Evidence trail: r4 (gload_lds+dbuf+barrier, no cap) = 204 VGPR, 2 blk/CU,
//   latency-bound 142 us; r5 (same + 128 cap) = ~100 dw/thread scratch spill,
//   192 us. The pipeline machinery WAS the register pressure.
// k-reduce: shfl_xor(32,16) + padded-LDS reduce -> t[8][16] (proven r3-r5).
// Phase 2: two half-passes of lf{0,1}[4] (32 regs) per column chunk; float2
//   stores contiguous per wave (proven r3-r5).
// __launch_bounds__(256,2): cap 128 VGPR = 4 waves/SIMD -> 4 blocks/CU,
// grid exactly resident in one occupancy wave.
// ---------------------------------------------------------------------------
__global__ __launch_bounds__(256, 2) void fused(const float* __restrict__ x,
                                                const float* __restrict__ rgt,
                                                const float* __restrict__ lft,
                                                const float* __restrict__ bias,
                                                float* __restrict__ out)
{
    __shared__ __align__(16) float red[64 * RST];  // 9216 B reduce scratch
    __shared__ __align__(16) float tl[ROWS * RK];  // t[8][16]

    const int tid = threadIdx.x;
    const int wv  = tid >> 6;
    const int l   = tid & 63;
    const int row0 = blockIdx.x * ROWS;

    // wave owns token rows {wv*2, wv*2+1}; lane owns k-cols l*4..l*4+3 / chunk
    const float* xr0 = x + (size_t)(row0 + wv * 2) * CIN + l * 4;
    const float* xr1 = xr0 + CIN;
    const float* rg  = rgt + l * 4;

    float acc[2][RK];
#pragma unroll
    for (int r = 0; r < RK; ++r) { acc[0][r] = 0.f; acc[1][r] = 0.f; }

#pragma unroll 2
    for (int c = 0; c < NCHUNK; ++c) {
        const int ko = c * CHUNK;
        const float4 xv0 = *(const float4*)&xr0[ko];
        const float4 xv1 = *(const float4*)&xr1[ko];
#pragma unroll
        for (int r = 0; r < RK; ++r) {
            const float4 rv = *(const float4*)&rg[(size_t)r * CIN + ko];
            acc[0][r] += rv.x * xv0.x; acc[0][r] += rv.y * xv0.y;
            acc[0][r] += rv.z * xv0.z; acc[0][r] += rv.w * xv0.w;
            acc[1][r] += rv.x * xv1.x; acc[1][r] += rv.y * xv1.y;
            acc[1][r] += rv.z * xv1.z; acc[1][r] += rv.w * xv1.w;
        }
    }

    // ---- k-reduce: 64 lanes -> 16 lane-groups (shfl) -> t[8][16] (LDS)
#pragma unroll
    for (int rr = 0; rr < 2; ++rr)
#pragma unroll
        for (int r = 0; r < RK; ++r) {
            acc[rr][r] += __shfl_xor(acc[rr][r], 32);
            acc[rr][r] += __shfl_xor(acc[rr][r], 16);
        }
    if (l < 16) {
#pragma unroll
        for (int rr = 0; rr < 2; ++rr)
#pragma unroll
            for (int q = 0; q < 4; ++q)
                *(float4*)&red[(wv * 16 + l) * RST + rr * 16 + q * 4] =
                    make_float4(acc[rr][q * 4 + 0], acc[rr][q * 4 + 1],
                                acc[rr][q * 4 + 2], acc[rr][q * 4 + 3]);
    }
    __syncthreads();
    if (tid < ROWS * RK) {
        const int row = tid >> 4, r = tid & 15;
        const int ws = row >> 1, rr = row & 1;
        float s = 0.f;
#pragma unroll
        for (int lp = 0; lp < 16; ++lp)
            s += red[(ws * 16 + lp) * RST + rr * 16 + r];
        tl[row * RK + r] = s;
    }
    __syncthreads();

    // ---- phase 2: out[8][4096] = t @ left^T + bias.
    // 4 column chunks x 2 half-passes; lf{0,1}[4] = 32 regs peak.
#pragma unroll 1
    for (int oc = 0; oc < 4; ++oc) {
#pragma unroll 1
        for (int h = 0; h < 2; ++h) {
            const int o0 = oc * 1024 + h * 512 + tid * 2;
            float4 lf0[4], lf1[4];
#pragma unroll
            for (int q = 0; q < 4; ++q) {
                lf0[q] = *(const float4*)&lft[(size_t)o0 * RK + q * 4];
                lf1[q] = *(const float4*)&lft[(size_t)(o0 + 1) * RK + q * 4];
            }
            const float2 bv = *(const float2*)&bias[o0];

#pragma unroll
            for (int rr = 0; rr < ROWS; ++rr) {
                float4 ts[4];
#pragma unroll
                for (int q = 0; q < 4; ++q)
                    ts[q] = ((const float4*)tl)[rr * 4 + q];   // uniform -> broadcast

                float r0 = bv.x, r1 = bv.y;
#pragma unroll
                for (int q = 0; q < 4; ++q) {
                    r0 += lf0[q].x * ts[q].x; r0 += lf0[q].y * ts[q].y;
                    r0 += lf0[q].z * ts[q].z; r0 += lf0[q].w * ts[q].w;
                    r1 += lf1[q].x * ts[q].x; r1 += lf1[q].y * ts[q].y;
                    r1 += lf1[q].z * ts[q].z; r1 += lf1[q].w * ts[q].w;
                }
                *(float2*)&out[(size_t)(row0 + rr) * COUT + o0] =
                    make_float2(r0, r1);
            }
        }
    }
}

extern "C" void kernel_launch(void* const* d_in, const int* in_sizes, int n_in,
                              void* d_out, int out_size, void* d_ws, size_t ws_size,
                              hipStream_t stream)
{
    const float* x    = (const float*)d_in[0];
    const float* lft  = (const float*)d_in[1];   // [COUT][RK]
    const float* rgt  = (const float*)d_in[2];   // [RK][CIN]
    const float* bias = (const float*)d_in[3];
    float*       out  = (float*)d_out;

    (void)d_ws; (void)ws_size;                   // workspace unused

    fused<<<dim3(NT / ROWS), dim3(256), 0, stream>>>(x, rgt, lft, bias, out);
}

// Round 7
// 358.422 us; speedup vs baseline: 1.0198x; 1.0198x over previous
//
#include <hip/hip_runtime.h>

#define NT    8192   // tokens
#define CIN   4096   // in_channel
#define COUT  4096   // out_channel
#define RK    16     // rank
#define ROWS  8      // tokens per block -> grid 1024 = 4 blocks/CU
#define CHUNK 256    // k per chunk (lane l owns k = c*256 + l*4 .. +3)
#define NCHUNK (CIN / CHUNK)   // 16
#define RST   36     // red row stride (floats): bank = 4*l -> 2-way = free

// ---------------------------------------------------------------------------
// Fused out = (x @ right^T) @ left^T + bias. One kernel, no workspace.
// grid = 1024 (8-token groups), 256 threads (4 waves).
//
// Phase 1 — barrier-free streaming, UNROLL 1. rgt is 256 KB (L1/L2-resident;
//   all 16 waves on a CU re-read the same 16 KB chunk). Per chunk iteration:
//   2 x-float4 (prefetched 1 chunk ahead: HBM latency covered) + 16 rgt
//   float4 (cache hits) + 128 fmac into acc[2][16].
//
//   REGISTER-WINDOW EVIDENCE (r4/r5/r6): LLVM hoists every independent load
//   in a straight-line body to the top. unroll 2 = 36 loads*4 + acc 32 +
//   addr ~16 = ~190 wanted -> under the 128 cap it spilled ~60 dw/thread
//   (r6: FETCH +60 MB, WRITE +64 MB); uncapped it took 204 VGPR and
//   occupancy died (r4: 11%, latency-bound). unroll 1 = 18 loads in flight
//   = ~114 peak -> fits the cap with zero spill BY SCHEDULE, not by luck.
//
// k-reduce: shfl_xor(32,16) + padded-LDS reduce -> t[8][16] (proven r3-r6).
// Phase 2: 4 col-chunks x 2 half-passes, lf{0,1}[4] = 32 regs; float2 stores
//   contiguous per wave (proven r3-r6, ~60 reg peak).
// __launch_bounds__(256,2): cap 128 VGPR = 4 waves/SIMD -> 4 blocks/CU,
//   grid exactly resident in one occupancy wave.
// ---------------------------------------------------------------------------
__global__ __launch_bounds__(256, 2) void fused(const float* __restrict__ x,
                                                const float* __restrict__ rgt,
                                                const float* __restrict__ lft,
                                                const float* __restrict__ bias,
                                                float* __restrict__ out)
{
    __shared__ __align__(16) float red[64 * RST];  // 9216 B reduce scratch
    __shared__ __align__(16) float tl[ROWS * RK];  // t[8][16]

    const int tid = threadIdx.x;
    const int wv  = tid >> 6;
    const int l   = tid & 63;
    const int row0 = blockIdx.x * ROWS;

    // wave owns token rows {wv*2, wv*2+1}; lane owns k-cols l*4..l*4+3 / chunk
    const float* xr0 = x + (size_t)(row0 + wv * 2) * CIN + l * 4;
    const float* xr1 = xr0 + CIN;
    const float* rg  = rgt + l * 4;

    float acc[2][RK];
#pragma unroll
    for (int r = 0; r < RK; ++r) { acc[0][r] = 0.f; acc[1][r] = 0.f; }

    // x prefetch registers (1 chunk ahead)
    float4 pfx0 = *(const float4*)&xr0[0];
    float4 pfx1 = *(const float4*)&xr1[0];

#pragma unroll 1
    for (int c = 0; c < NCHUNK; ++c) {
        const int ko = c * CHUNK;
        const float4 xv0 = pfx0;
        const float4 xv1 = pfx1;
        if (c + 1 < NCHUNK) {
            pfx0 = *(const float4*)&xr0[ko + CHUNK];
            pfx1 = *(const float4*)&xr1[ko + CHUNK];
        }
#pragma unroll
        for (int r = 0; r < RK; ++r) {
            const float4 rv = *(const float4*)&rg[(size_t)r * CIN + ko];
            acc[0][r] += rv.x * xv0.x; acc[0][r] += rv.y * xv0.y;
            acc[0][r] += rv.z * xv0.z; acc[0][r] += rv.w * xv0.w;
            acc[1][r] += rv.x * xv1.x; acc[1][r] += rv.y * xv1.y;
            acc[1][r] += rv.z * xv1.z; acc[1][r] += rv.w * xv1.w;
        }
    }

    // ---- k-reduce: 64 lanes -> 16 lane-groups (shfl) -> t[8][16] (LDS)
#pragma unroll
    for (int rr = 0; rr < 2; ++rr)
#pragma unroll
        for (int r = 0; r < RK; ++r) {
            acc[rr][r] += __shfl_xor(acc[rr][r], 32);
            acc[rr][r] += __shfl_xor(acc[rr][r], 16);
        }
    if (l < 16) {
#pragma unroll
        for (int rr = 0; rr < 2; ++rr)
#pragma unroll
            for (int q = 0; q < 4; ++q)
                *(float4*)&red[(wv * 16 + l) * RST + rr * 16 + q * 4] =
                    make_float4(acc[rr][q * 4 + 0], acc[rr][q * 4 + 1],
                                acc[rr][q * 4 + 2], acc[rr][q * 4 + 3]);
    }
    __syncthreads();
    if (tid < ROWS * RK) {
        const int row = tid >> 4, r = tid & 15;
        const int ws = row >> 1, rr = row & 1;
        float s = 0.f;
#pragma unroll
        for (int lp = 0; lp < 16; ++lp)
            s += red[(ws * 16 + lp) * RST + rr * 16 + r];
        tl[row * RK + r] = s;
    }
    __syncthreads();

    // ---- phase 2: out[8][4096] = t @ left^T + bias.
    // 4 column chunks x 2 half-passes; lf{0,1}[4] = 32 regs peak.
#pragma unroll 1
    for (int oc = 0; oc < 4; ++oc) {
#pragma unroll 1
        for (int h = 0; h < 2; ++h) {
            const int o0 = oc * 1024 + h * 512 + tid * 2;
            float4 lf0[4], lf1[4];
#pragma unroll
            for (int q = 0; q < 4; ++q) {
                lf0[q] = *(const float4*)&lft[(size_t)o0 * RK + q * 4];
                lf1[q] = *(const float4*)&lft[(size_t)(o0 + 1) * RK + q * 4];
            }
            const float2 bv = *(const float2*)&bias[o0];

#pragma unroll
            for (int rr = 0; rr < ROWS; ++rr) {
                float4 ts[4];
#pragma unroll
                for (int q = 0; q < 4; ++q)
                    ts[q] = ((const float4*)tl)[rr * 4 + q];   // uniform -> broadcast

                float r0 = bv.x, r1 = bv.y;
#pragma unroll
                for (int q = 0; q < 4; ++q) {
                    r0 += lf0[q].x * ts[q].x; r0 += lf0[q].y * ts[q].y;
                    r0 += lf0[q].z * ts[q].z; r0 += lf0[q].w * ts[q].w;
                    r1 += lf1[q].x * ts[q].x; r1 += lf1[q].y * ts[q].y;
                    r1 += lf1[q].z * ts[q].z; r1 += lf1[q].w * ts[q].w;
                }
                *(float2*)&out[(size_t)(row0 + rr) * COUT + o0] =
                    make_float2(r0, r1);
            }
        }
    }
}

extern "C" void kernel_launch(void* const* d_in, const int* in_sizes, int n_in,
                              void* d_out, int out_size, void* d_ws, size_t ws_size,
                              hipStream_t stream)
{
    const float* x    = (const float*)d_in[0];
    const float* lft  = (const float*)d_in[1];   // [COUT][RK]
    const float* rgt  = (const float*)d_in[2];   // [RK][CIN]
    const float* bias = (const float*)d_in[3];
    float*       out  = (float*)d_out;

    (void)d_ws; (void)ws_size;                   // workspace unused

    fused<<<dim3(NT / ROWS), dim3(256), 0, stream>>>(x, rgt, lft, bias, out);
}

// Round 8
// 356.097 us; speedup vs baseline: 1.0265x; 1.0065x over previous
//
#include <hip/hip_runtime.h>

#define NT    8192   // tokens
#define CIN   4096   // in_channel
#define COUT  4096   // out_channel
#define RK    16     // rank
#define ROWS  8      // tokens per block -> grid 1024 = 4 blocks/CU
#define CHUNK 256    // k per chunk (lane l owns k = c*256 + l*4 .. +3)
#define NCHUNK (CIN / CHUNK)   // 16
#define RST   36     // red row stride (floats): bank = 4*l -> 2-way = free

// ---------------------------------------------------------------------------
// Fused out = (x @ right^T) @ left^T + bias. One kernel, no workspace.
// grid = 1024 (8-token groups), 256 threads (4 waves).
//
// Phase 1 — barrier-free streaming with a PINNED 8-load window.
//   rgt (256 KB) is L1/L2-resident; x is a pure HBM stream (prefetched one
//   chunk ahead). Per chunk: 2 halves of {8 rgt float4 loads + 64 fmac},
//   separated by sched_barrier(0).
//
//   SPILL LADDER EVIDENCE: r6 (unroll 2) and r7 (unroll 1) both show
//   WRITE = 134 MB(out) + 65 MB(scratch) == ~4 spilled dwords per chunk-iter
//   per thread, invariant under unroll -> the scheduler's load window (16 rv
//   in flight = 64 VGPR) + acc(32) + xv/pfx(16) + addr(~12) lands a hair
//   over the 128 cap. Halving the window to 8 rv (32 VGPR) makes the live
//   set ~90. sched_barrier(0) stops LLVM re-hoisting half-1's loads above
//   half-0's fmacs (it re-merges split loops otherwise).
//
// k-reduce: shfl_xor(32,16) + padded-LDS reduce -> t[8][16] (proven r3-r7).
// Phase 2: 4 col-chunks x 2 half-passes, lf{0,1}[4] = 32 regs; float2 stores
//   contiguous per wave (proven r3-r7; r4 ran it spill-free).
// __launch_bounds__(256,2): cap 128 VGPR = 4 waves/SIMD -> 4 blocks/CU,
//   grid exactly resident in one occupancy wave.
// ---------------------------------------------------------------------------
__global__ __launch_bounds__(256, 2) void fused(const float* __restrict__ x,
                                                const float* __restrict__ rgt,
                                                const float* __restrict__ lft,
                                                const float* __restrict__ bias,
                                                float* __restrict__ out)
{
    __shared__ __align__(16) float red[64 * RST];  // 9216 B reduce scratch
    __shared__ __align__(16) float tl[ROWS * RK];  // t[8][16]

    const int tid = threadIdx.x;
    const int wv  = tid >> 6;
    const int l   = tid & 63;
    const int row0 = blockIdx.x * ROWS;

    // wave owns token rows {wv*2, wv*2+1}; lane owns k-cols l*4..l*4+3 / chunk
    const float* xr0 = x + (size_t)(row0 + wv * 2) * CIN + l * 4;
    const float* xr1 = xr0 + CIN;
    const float* rg  = rgt + l * 4;

    float acc[2][RK];
#pragma unroll
    for (int r = 0; r < RK; ++r) { acc[0][r] = 0.f; acc[1][r] = 0.f; }

    // x prefetch registers (1 chunk ahead)
    float4 pfx0 = *(const float4*)&xr0[0];
    float4 pfx1 = *(const float4*)&xr1[0];

#pragma unroll 1
    for (int c = 0; c < NCHUNK; ++c) {
        const int ko = c * CHUNK;
        const float4 xv0 = pfx0;
        const float4 xv1 = pfx1;
        if (c + 1 < NCHUNK) {
            pfx0 = *(const float4*)&xr0[ko + CHUNK];
            pfx1 = *(const float4*)&xr1[ko + CHUNK];
        }
        // ---- half 0: r = 0..7 (8 loads in flight, 32 VGPR)
        {
            float4 rv[8];
#pragma unroll
            for (int j = 0; j < 8; ++j)
                rv[j] = *(const float4*)&rg[(size_t)j * CIN + ko];
#pragma unroll
            for (int j = 0; j < 8; ++j) {
                acc[0][j] += rv[j].x * xv0.x; acc[0][j] += rv[j].y * xv0.y;
                acc[0][j] += rv[j].z * xv0.z; acc[0][j] += rv[j].w * xv0.w;
                acc[1][j] += rv[j].x * xv1.x; acc[1][j] += rv[j].y * xv1.y;
                acc[1][j] += rv[j].z * xv1.z; acc[1][j] += rv[j].w * xv1.w;
            }
        }
        __builtin_amdgcn_sched_barrier(0);   // pin: half-1 loads stay below
        // ---- half 1: r = 8..15
        {
            float4 rv[8];
#pragma unroll
            for (int j = 0; j < 8; ++j)
                rv[j] = *(const float4*)&rg[(size_t)(j + 8) * CIN + ko];
#pragma unroll
            for (int j = 0; j < 8; ++j) {
                acc[0][j + 8] += rv[j].x * xv0.x; acc[0][j + 8] += rv[j].y * xv0.y;
                acc[0][j + 8] += rv[j].z * xv0.z; acc[0][j + 8] += rv[j].w * xv0.w;
                acc[1][j + 8] += rv[j].x * xv1.x; acc[1][j + 8] += rv[j].y * xv1.y;
                acc[1][j + 8] += rv[j].z * xv1.z; acc[1][j + 8] += rv[j].w * xv1.w;
            }
        }
        __builtin_amdgcn_sched_barrier(0);   // pin loop-body boundary
    }

    // ---- k-reduce: 64 lanes -> 16 lane-groups (shfl) -> t[8][16] (LDS)
#pragma unroll
    for (int rr = 0; rr < 2; ++rr)
#pragma unroll
        for (int r = 0; r < RK; ++r) {
            acc[rr][r] += __shfl_xor(acc[rr][r], 32);
            acc[rr][r] += __shfl_xor(acc[rr][r], 16);
        }
    if (l < 16) {
#pragma unroll
        for (int rr = 0; rr < 2; ++rr)
#pragma unroll
            for (int q = 0; q < 4; ++q)
                *(float4*)&red[(wv * 16 + l) * RST + rr * 16 + q * 4] =
                    make_float4(acc[rr][q * 4 + 0], acc[rr][q * 4 + 1],
                                acc[rr][q * 4 + 2], acc[rr][q * 4 + 3]);
    }
    __syncthreads();
    if (tid < ROWS * RK) {
        const int row = tid >> 4, r = tid & 15;
        const int ws = row >> 1, rr = row & 1;
        float s = 0.f;
#pragma unroll
        for (int lp = 0; lp < 16; ++lp)
            s += red[(ws * 16 + lp) * RST + rr * 16 + r];
        tl[row * RK + r] = s;
    }
    __syncthreads();

    // ---- phase 2: out[8][4096] = t @ left^T + bias.
    // 4 column chunks x 2 half-passes; lf{0,1}[4] = 32 regs peak.
#pragma unroll 1
    for (int oc = 0; oc < 4; ++oc) {
#pragma unroll 1
        for (int h = 0; h < 2; ++h) {
            const int o0 = oc * 1024 + h * 512 + tid * 2;
            float4 lf0[4], lf1[4];
#pragma unroll
            for (int q = 0; q < 4; ++q) {
                lf0[q] = *(const float4*)&lft[(size_t)o0 * RK + q * 4];
                lf1[q] = *(const float4*)&lft[(size_t)(o0 + 1) * RK + q * 4];
            }
            const float2 bv = *(const float2*)&bias[o0];

#pragma unroll
            for (int rr = 0; rr < ROWS; ++rr) {
                float4 ts[4];
#pragma unroll
                for (int q = 0; q < 4; ++q)
                    ts[q] = ((const float4*)tl)[rr * 4 + q];   // uniform -> broadcast

                float r0 = bv.x, r1 = bv.y;
#pragma unroll
                for (int q = 0; q < 4; ++q) {
                    r0 += lf0[q].x * ts[q].x; r0 += lf0[q].y * ts[q].y;
                    r0 += lf0[q].z * ts[q].z; r0 += lf0[q].w * ts[q].w;
                    r1 += lf1[q].x * ts[q].x; r1 += lf1[q].y * ts[q].y;
                    r1 += lf1[q].z * ts[q].z; r1 += lf1[q].w * ts[q].w;
                }
                *(float2*)&out[(size_t)(row0 + rr) * COUT + o0] =
                    make_float2(r0, r1);
            }
        }
    }
}

extern "C" void kernel_launch(void* const* d_in, const int* in_sizes, int n_in,
                              void* d_out, int out_size, void* d_ws, size_t ws_size,
                              hipStream_t stream)
{
    const float* x    = (const float*)d_in[0];
    const float* lft  = (const float*)d_in[1];   // [COUT][RK]
    const float* rgt  = (const float*)d_in[2];   // [RK][CIN]
    const float* bias = (const float*)d_in[3];
    float*       out  = (float*)d_out;

    (void)d_ws; (void)ws_size;                   // workspace unused

    fused<<<dim3(NT / ROWS), dim3(256), 0, stream>>>(x, rgt, lft, bias, out);
}